// Round 1
// baseline (313.950 us; speedup 1.0000x reference)
//
#include <hip/hip_runtime.h>
#include <cmath>

#define NUM_CLS 58

// ---------------- weight binarization ----------------
// w: [128][128][3][3] floats -> out: [oc][ky*3+kx][2] u64 (bit ic = sign>=0)
__global__ void prep_w3x3(const float* __restrict__ w, unsigned long long* __restrict__ out) {
    int item = blockIdx.x;            // oc*9 + k,   k = ky*3+kx
    int lane = threadIdx.x;           // 64 threads
    int oc = item / 9, k = item % 9;
    const float* base = w + (size_t)oc * 1152 + k;   // element ic at base[ic*9]
    unsigned long long b0 = __ballot(base[lane * 9] >= 0.f);
    unsigned long long b1 = __ballot(base[(lane + 64) * 9] >= 0.f);
    if (lane == 0) { out[item * 2] = b0; out[item * 2 + 1] = b1; }
}

// w: [128][128] floats -> out: [oc][2] u64
__global__ void prep_w1x1(const float* __restrict__ w, unsigned long long* __restrict__ out) {
    int oc = blockIdx.x;
    int lane = threadIdx.x;
    unsigned long long b0 = __ballot(w[oc * 128 + lane] >= 0.f);
    unsigned long long b1 = __ballot(w[oc * 128 + lane + 64] >= 0.f);
    if (lane == 0) { out[oc * 2] = b0; out[oc * 2 + 1] = b1; }
}

// ---------------- stage 1: float conv0 + maxpool2 + sign-pack ----------------
// x: [B][3][32][32], w0: [128][3][3][3] -> bits1: [B][15*15][2] u64
__global__ __launch_bounds__(256) void conv0_pool_pack(
    const float* __restrict__ x, const float* __restrict__ w0,
    unsigned long long* __restrict__ bits1) {
    __shared__ float xs[3 * 32 * 32];
    int b = blockIdx.x;
    int tid = threadIdx.x;
    const float* xb = x + (size_t)b * 3072;
    for (int i = tid; i < 3072; i += 256) xs[i] = xb[i];
    int lane = tid & 63, wave = tid >> 6;
    int half = wave & 1, pair = wave >> 1;
    int oc = half * 64 + lane;
    float wr[27];
#pragma unroll
    for (int j = 0; j < 27; j++) wr[j] = w0[oc * 27 + j];
    __syncthreads();
    for (int p = pair; p < 225; p += 2) {
        int py = p / 15, px = p % 15;
        float xp[3][16];  // 4x4 input patch per channel (rows 2py.., cols 2px..)
#pragma unroll
        for (int c = 0; c < 3; c++)
#pragma unroll
            for (int yy = 0; yy < 4; yy++)
#pragma unroll
                for (int xx = 0; xx < 4; xx++)
                    xp[c][yy * 4 + xx] = xs[c * 1024 + (2 * py + yy) * 32 + (2 * px + xx)];
        bool pos = false;
#pragma unroll
        for (int dy = 0; dy < 2; dy++)
#pragma unroll
            for (int dx = 0; dx < 2; dx++) {
                float s = 0.f;
#pragma unroll
                for (int c = 0; c < 3; c++)
#pragma unroll
                    for (int ky = 0; ky < 3; ky++)
#pragma unroll
                        for (int kx = 0; kx < 3; kx++)
                            s = fmaf(xp[c][(dy + ky) * 4 + dx + kx], wr[c * 9 + ky * 3 + kx], s);
                if (__builtin_expect(fabsf(s) < 1e-4f, 0)) {
                    // borderline: recompute in f64 so the sign matches a float64 reference
                    double sd = 0.0;
                    for (int c = 0; c < 3; c++)
                        for (int ky = 0; ky < 3; ky++)
                            for (int kx = 0; kx < 3; kx++)
                                sd += (double)xp[c][(dy + ky) * 4 + dx + kx] * (double)wr[c * 9 + ky * 3 + kx];
                    pos |= (sd >= 0.0);
                } else {
                    pos |= (s >= 0.f);
                }
            }
        unsigned long long m = __ballot(pos);
        if (lane == 0) bits1[(size_t)(b * 225 + p) * 2 + half] = m;
    }
}

// ---------------- stage 2: binconv1 (15->13) + maxpool2 (->6) + pack ----------------
__global__ __launch_bounds__(256) void binconv1_pool_pack(
    const unsigned long long* __restrict__ bits1,
    const unsigned long long* __restrict__ wb,   // [128][9][2]
    unsigned long long* __restrict__ bits2) {    // [B][36][2]
    __shared__ unsigned long long in_s[225 * 2];
    int b = blockIdx.x;
    int tid = threadIdx.x;
    const unsigned long long* ib = bits1 + (size_t)b * 450;
    for (int i = tid; i < 450; i += 256) in_s[i] = ib[i];
    int lane = tid & 63, wave = tid >> 6, half = wave & 1, pair = wave >> 1;
    int oc = half * 64 + lane;
    unsigned long long wr[18];
#pragma unroll
    for (int j = 0; j < 18; j++) wr[j] = wb[oc * 18 + j];
    __syncthreads();
    for (int p = pair; p < 36; p += 2) {
        int py = p / 6, px = p % 6;
        unsigned long long xp[4][4][2];
#pragma unroll
        for (int yy = 0; yy < 4; yy++)
#pragma unroll
            for (int xx = 0; xx < 4; xx++) {
                int idx = ((2 * py + yy) * 15 + (2 * px + xx)) * 2;
                xp[yy][xx][0] = in_s[idx];
                xp[yy][xx][1] = in_s[idx + 1];
            }
        bool pos = false;
#pragma unroll
        for (int dy = 0; dy < 2; dy++)
#pragma unroll
            for (int dx = 0; dx < 2; dx++) {
                int P = 0;
#pragma unroll
                for (int ky = 0; ky < 3; ky++)
#pragma unroll
                    for (int kx = 0; kx < 3; kx++) {
                        P += __popcll(xp[dy + ky][dx + kx][0] ^ wr[(ky * 3 + kx) * 2]);
                        P += __popcll(xp[dy + ky][dx + kx][1] ^ wr[(ky * 3 + kx) * 2 + 1]);
                    }
                pos |= (P <= 576);   // 1152 - 2P >= 0
            }
        unsigned long long m = __ballot(pos);
        if (lane == 0) bits2[(size_t)(b * 36 + p) * 2 + half] = m;
    }
}

// ---------------- stage 3: binconv2 (6->4) + maxpool(2,s1) (->3) + pack ----------------
__global__ __launch_bounds__(256) void binconv2_pool_pack(
    const unsigned long long* __restrict__ bits2,
    const unsigned long long* __restrict__ wb,   // [128][9][2]
    unsigned long long* __restrict__ bits3) {    // [B][9][2]
    __shared__ unsigned long long in_s[36 * 2];
    int b = blockIdx.x;
    int tid = threadIdx.x;
    const unsigned long long* ib = bits2 + (size_t)b * 72;
    for (int i = tid; i < 72; i += 256) in_s[i] = ib[i];
    int lane = tid & 63, wave = tid >> 6, half = wave & 1, pair = wave >> 1;
    int oc = half * 64 + lane;
    unsigned long long wr[18];
#pragma unroll
    for (int j = 0; j < 18; j++) wr[j] = wb[oc * 18 + j];
    __syncthreads();
    for (int p = pair; p < 9; p += 2) {
        int py = p / 3, px = p % 3;
        bool pos = false;
#pragma unroll
        for (int dy = 0; dy < 2; dy++)
#pragma unroll
            for (int dx = 0; dx < 2; dx++) {
                int P = 0;
#pragma unroll
                for (int ky = 0; ky < 3; ky++)
#pragma unroll
                    for (int kx = 0; kx < 3; kx++) {
                        int iy = py + dy + ky, ix = px + dx + kx;
                        int idx = (iy * 6 + ix) * 2;
                        P += __popcll(in_s[idx] ^ wr[(ky * 3 + kx) * 2]);
                        P += __popcll(in_s[idx + 1] ^ wr[(ky * 3 + kx) * 2 + 1]);
                    }
                pos |= (P <= 576);
            }
        unsigned long long m = __ballot(pos);
        if (lane == 0) bits3[(size_t)(b * 9 + p) * 2 + half] = m;
    }
}

// ---------------- stage 4: binconv3 (3->1) + binconv4 (1x1) + relu + w5 + softmax ----------------
__global__ __launch_bounds__(128) void tail_kernel(
    const unsigned long long* __restrict__ bits3, // [B][9][2]
    const unsigned long long* __restrict__ wb3,   // [128][9][2]
    const unsigned long long* __restrict__ wb4,   // [128][2]
    const float* __restrict__ w5,                 // [58][128]
    float* __restrict__ out) {                    // [B][58]
    __shared__ unsigned long long in_s[18];
    __shared__ unsigned long long bits4_s[2];
    __shared__ float r_s[128];
    __shared__ float l_s[NUM_CLS];
    __shared__ float e_s[NUM_CLS];
    int b = blockIdx.x;
    int t = threadIdx.x;              // == oc
    int lane = t & 63, wave = t >> 6;
    if (t < 18) in_s[t] = bits3[(size_t)b * 18 + t];
    __syncthreads();
    int P = 0;
#pragma unroll
    for (int k = 0; k < 9; k++) {
        P += __popcll(in_s[k * 2] ^ wb3[t * 18 + k * 2]);
        P += __popcll(in_s[k * 2 + 1] ^ wb3[t * 18 + k * 2 + 1]);
    }
    unsigned long long m = __ballot(P <= 576);
    if (lane == 0) bits4_s[wave] = m;
    __syncthreads();
    unsigned long long i0 = bits4_s[0], i1 = bits4_s[1];
    int v = 128 - 2 * (int)(__popcll(i0 ^ wb4[t * 2]) + __popcll(i1 ^ wb4[t * 2 + 1]));
    r_s[t] = v > 0 ? (float)v : 0.f;   // relu
    __syncthreads();
    if (t < NUM_CLS) {
        float l = 0.f;
#pragma unroll 8
        for (int k = 0; k < 128; k++) l = fmaf(w5[t * 128 + k], r_s[k], l);
        l_s[t] = l;
    }
    __syncthreads();
    if (t < NUM_CLS) {
        float mx = -1e30f;
        for (int k = 0; k < NUM_CLS; k++) mx = fmaxf(mx, l_s[k]);
        e_s[t] = expf(l_s[t] - mx);
    }
    __syncthreads();
    if (t < NUM_CLS) {
        float sum = 0.f;
        for (int k = 0; k < NUM_CLS; k++) sum += e_s[k];
        out[(size_t)b * NUM_CLS + t] = e_s[t] / sum;
    }
}

extern "C" void kernel_launch(void* const* d_in, const int* in_sizes, int n_in,
                              void* d_out, int out_size, void* d_ws, size_t ws_size,
                              hipStream_t stream) {
    const float* x  = (const float*)d_in[0];
    const float* w0 = (const float*)d_in[1];
    const float* w1 = (const float*)d_in[2];
    const float* w2 = (const float*)d_in[3];
    const float* w3 = (const float*)d_in[4];
    const float* w4 = (const float*)d_in[5];
    const float* w5 = (const float*)d_in[6];
    float* out = (float*)d_out;

    int B = in_sizes[0] / 3072;   // 1024

    // workspace carve-up (all 256B-aligned)
    size_t off = 0;
    auto carve = [&](size_t bytes) {
        void* p = (char*)d_ws + off;
        off += (bytes + 255) & ~(size_t)255;
        return p;
    };
    unsigned long long* bits1 = (unsigned long long*)carve((size_t)B * 450 * 8);
    unsigned long long* bits2 = (unsigned long long*)carve((size_t)B * 72 * 8);
    unsigned long long* bits3 = (unsigned long long*)carve((size_t)B * 18 * 8);
    unsigned long long* wb1   = (unsigned long long*)carve(1152 * 2 * 8);
    unsigned long long* wb2   = (unsigned long long*)carve(1152 * 2 * 8);
    unsigned long long* wb3   = (unsigned long long*)carve(1152 * 2 * 8);
    unsigned long long* wb4   = (unsigned long long*)carve(128 * 2 * 8);
    (void)ws_size; (void)n_in; (void)out_size;

    prep_w3x3<<<1152, 64, 0, stream>>>(w1, wb1);
    prep_w3x3<<<1152, 64, 0, stream>>>(w2, wb2);
    prep_w3x3<<<1152, 64, 0, stream>>>(w3, wb3);
    prep_w1x1<<<128, 64, 0, stream>>>(w4, wb4);

    conv0_pool_pack<<<B, 256, 0, stream>>>(x, w0, bits1);
    binconv1_pool_pack<<<B, 256, 0, stream>>>(bits1, wb1, bits2);
    binconv2_pool_pack<<<B, 256, 0, stream>>>(bits2, wb2, bits3);
    tail_kernel<<<B, 128, 0, stream>>>(bits3, wb3, wb4, w5, out);
}